// Round 1
// baseline (160.731 us; speedup 1.0000x reference)
//
#include <hip/hip_runtime.h>

// DifferentiableProjectionLayer: alternating projection (box+simplex, then 8
// disjoint group projections) on 262144 independent rows of 64 assets.
//
// Mapping: 8 lanes per row; lane c owns the 8 assets of group c
// (assets c, c+8, ..., c+56) => group dot products / updates are lane-local.
// Row sum for the simplex shift is a 3-step shfl_xor butterfly over the
// 8-lane subgroup. The reference's recomputed dot after the upper-bound
// update is evaluated analytically: Aw2 = Aw - d1*||a||^2.

#define NA 64
#define NG 8

__global__ __launch_bounds__(256) void proj_kernel(
    const float* __restrict__ x,
    const float* __restrict__ box_lb,
    const float* __restrict__ box_ub,
    const float* __restrict__ group_A,
    const float* __restrict__ group_lb,
    const float* __restrict__ group_ub,
    const int*  __restrict__ num_iter,
    float* __restrict__ out,
    int nrows)
{
    const int t = blockIdx.x * blockDim.x + threadIdx.x;
    const int r = t >> 3;     // row index
    const int c = t & 7;      // group / asset-class index
    if (r >= nrows) return;

    const float* __restrict__ xr = x + (size_t)r * NA;
    float* __restrict__ outr = out + (size_t)r * NA;

    float w[8], lbv[8], ubv[8], av[8];
#pragma unroll
    for (int k = 0; k < 8; ++k) {
        const int j = k * 8 + c;            // asset index owned by this lane
        w[k]   = xr[j];
        lbv[k] = box_lb[j];
        ubv[k] = box_ub[j];
        av[k]  = group_A[c * NA + j];       // A[c][j] (structural nonzeros)
    }
    const float glb = group_lb[c];
    const float gub = group_ub[c];

    float ns = 0.f, sumA = 0.f;
#pragma unroll
    for (int k = 0; k < 8; ++k) { ns = fmaf(av[k], av[k], ns); sumA += av[k]; }
    const float inv = 1.0f / (ns + 1e-9f);  // matches reference EPS

    const int iters = *num_iter;

    for (int it = 0; it < iters; ++it) {
        // box clip + lane-local sums
        float s_loc = 0.f, dota = 0.f;
#pragma unroll
        for (int k = 0; k < 8; ++k) {
            w[k] = fminf(fmaxf(w[k], lbv[k]), ubv[k]);   // clip(w, lb, ub)
            s_loc += w[k];
            dota = fmaf(av[k], w[k], dota);
        }
        // row sum across the 8 lanes of this row
        float S = s_loc;
        S += __shfl_xor(S, 1);
        S += __shfl_xor(S, 2);
        S += __shfl_xor(S, 4);
        const float shift = (S - 1.0f) * (1.0f / NA);

        // group dot on the box-projected w: Aw = sum(a*c) - shift*sum(a)
        const float Aw = dota - shift * sumA;
        const float d1  = (Aw > gub) ? (Aw - gub) * inv : 0.0f;
        const float Aw2 = fmaf(-d1, ns, Aw);             // analytic recompute
        const float d2  = (Aw2 < glb) ? (Aw2 - glb) * inv : 0.0f;
        const float d   = d1 + d2;

        // fused update: w = clip(w) - shift - d*a
#pragma unroll
        for (int k = 0; k < 8; ++k) {
            w[k] = w[k] - fmaf(d, av[k], shift);
        }
    }

    // final box_simplex
    float s_loc = 0.f;
#pragma unroll
    for (int k = 0; k < 8; ++k) {
        w[k] = fminf(fmaxf(w[k], lbv[k]), ubv[k]);
        s_loc += w[k];
    }
    float S = s_loc;
    S += __shfl_xor(S, 1);
    S += __shfl_xor(S, 2);
    S += __shfl_xor(S, 4);
    const float shift = (S - 1.0f) * (1.0f / NA);

#pragma unroll
    for (int k = 0; k < 8; ++k) {
        outr[k * 8 + c] = w[k] - shift;
    }
}

extern "C" void kernel_launch(void* const* d_in, const int* in_sizes, int n_in,
                              void* d_out, int out_size, void* d_ws, size_t ws_size,
                              hipStream_t stream) {
    const float* x        = (const float*)d_in[0];
    const float* box_lb   = (const float*)d_in[1];
    const float* box_ub   = (const float*)d_in[2];
    const float* group_A  = (const float*)d_in[3];
    const float* group_lb = (const float*)d_in[4];
    const float* group_ub = (const float*)d_in[5];
    const int*   num_iter = (const int*)d_in[6];
    float* out = (float*)d_out;

    const int nrows = in_sizes[0] / NA;          // 262144
    const int total_threads = nrows * 8;         // 8 lanes per row
    const int block = 256;
    const int grid = (total_threads + block - 1) / block;

    proj_kernel<<<grid, block, 0, stream>>>(x, box_lb, box_ub, group_A,
                                            group_lb, group_ub, num_iter,
                                            out, nrows);
}

// Round 2
// 140.898 us; speedup vs baseline: 1.1408x; 1.1408x over previous
//
#include <hip/hip_runtime.h>

// DifferentiableProjectionLayer: 262144 independent rows of 64 assets,
// 20 iters of {box clip + simplex shift + 8 disjoint group projections}.
//
// Mapping: 8 lanes per row; lane c owns the 8 assets of group c
// (assets c, c+8, ..., c+56) => group dots / updates are lane-local.
// Row sum: xor1/xor2 via DPP quad_perm adds, xor4 via one ds_swizzle.
// Fast path (wave-uniform, checked at runtime): A values all 1.0 and
// lb<=ub  =>  dot(a,w) == sum(w), med3 clip, update w -= (shift+d).

#define NA 64

__device__ __forceinline__ float row8_allreduce_sum(float v) {
    // butterfly over the 8-lane row group: xor 1, 2 (DPP quad_perm), xor 4 (swizzle)
    int j = __builtin_amdgcn_update_dpp(0, __builtin_bit_cast(int, v),
                                        0xB1 /*quad_perm [1,0,3,2]*/, 0xF, 0xF, true);
    v += __builtin_bit_cast(float, j);
    j = __builtin_amdgcn_update_dpp(0, __builtin_bit_cast(int, v),
                                    0x4E /*quad_perm [2,3,0,1]*/, 0xF, 0xF, true);
    v += __builtin_bit_cast(float, j);
    j = __builtin_amdgcn_ds_swizzle(__builtin_bit_cast(int, v), 0x101F /*xor 4*/);
    v += __builtin_bit_cast(float, j);
    return v;
}

template <bool FAST>
__device__ __forceinline__ void run_iters(float (&w)[8], const float (&lbv)[8],
                                          const float (&ubv)[8], const float (&av)[8],
                                          float glb, float gub, float sumA,
                                          float ns, float inv, int iters) {
    const float inv_na = 1.0f / NA;
    for (int it = 0; it < iters; ++it) {
        // box clip
#pragma unroll
        for (int k = 0; k < 8; ++k) {
            if (FAST)
                w[k] = __builtin_amdgcn_fmed3f(w[k], lbv[k], ubv[k]);
            else
                w[k] = fminf(fmaxf(w[k], lbv[k]), ubv[k]);
        }
        // lane-local sums (tree)
        const float s01 = w[0] + w[1], s23 = w[2] + w[3];
        const float s45 = w[4] + w[5], s67 = w[6] + w[7];
        const float s_loc = (s01 + s23) + (s45 + s67);
        float dota;
        if (FAST) {
            dota = s_loc;              // all a == 1 on owned positions
        } else {
            dota = 0.f;
#pragma unroll
            for (int k = 0; k < 8; ++k) dota = fmaf(av[k], w[k], dota);
        }
        // row sum across the 8 lanes
        const float S = row8_allreduce_sum(s_loc);
        const float shift = fmaf(S, inv_na, -inv_na);   // (S-1)/64

        // group projection (upper, then analytic recompute, then lower)
        const float Aw  = fmaf(-sumA, shift, dota);
        const float d1  = fmaxf(Aw - gub, 0.0f) * inv;
        const float Aw2 = fmaf(-d1, ns, Aw);
        const float d2  = fminf(Aw2 - glb, 0.0f) * inv;
        const float d   = d1 + d2;

        if (FAST) {
            const float u = shift + d;                  // a == 1
#pragma unroll
            for (int k = 0; k < 8; ++k) w[k] -= u;
        } else {
#pragma unroll
            for (int k = 0; k < 8; ++k) w[k] -= fmaf(d, av[k], shift);
        }
    }
}

__global__ __launch_bounds__(256) void proj_kernel(
    const float* __restrict__ x,
    const float* __restrict__ box_lb,
    const float* __restrict__ box_ub,
    const float* __restrict__ group_A,
    const float* __restrict__ group_lb,
    const float* __restrict__ group_ub,
    const int*  __restrict__ num_iter,
    float* __restrict__ out,
    int nrows)
{
    const int t = blockIdx.x * blockDim.x + threadIdx.x;
    const int r = t >> 3;     // row index
    const int c = t & 7;      // group / asset-class index
    if (r >= nrows) return;

    const float* __restrict__ xr = x + (size_t)r * NA;
    float* __restrict__ outr = out + (size_t)r * NA;

    float w[8], lbv[8], ubv[8], av[8];
#pragma unroll
    for (int k = 0; k < 8; ++k) {
        const int j = k * 8 + c;            // asset owned by this lane
        w[k]   = xr[j];
        lbv[k] = box_lb[j];
        ubv[k] = box_ub[j];
        av[k]  = group_A[c * NA + j];       // A[c][j] (structural positions)
    }
    const float glb = group_lb[c];
    const float gub = group_ub[c];

    float ns = 0.f, sumA = 0.f;
#pragma unroll
    for (int k = 0; k < 8; ++k) { ns = fmaf(av[k], av[k], ns); sumA += av[k]; }
    const float inv = 1.0f / (ns + 1e-9f);  // reference EPS

    const int iters = *num_iter;

    // wave-uniform fast-path check: a==1 everywhere owned, box bounds ordered
    bool f = true;
#pragma unroll
    for (int k = 0; k < 8; ++k)
        f = f && (av[k] == 1.0f) && (lbv[k] <= ubv[k]);
    if (__all(f)) {
        run_iters<true>(w, lbv, ubv, av, glb, gub, sumA, ns, inv, iters);
    } else {
        run_iters<false>(w, lbv, ubv, av, glb, gub, sumA, ns, inv, iters);
    }

    // final box_simplex
#pragma unroll
    for (int k = 0; k < 8; ++k)
        w[k] = fminf(fmaxf(w[k], lbv[k]), ubv[k]);
    const float s01 = w[0] + w[1], s23 = w[2] + w[3];
    const float s45 = w[4] + w[5], s67 = w[6] + w[7];
    const float S = row8_allreduce_sum((s01 + s23) + (s45 + s67));
    const float shift = fmaf(S, 1.0f / NA, -1.0f / NA);

#pragma unroll
    for (int k = 0; k < 8; ++k)
        outr[k * 8 + c] = w[k] - shift;
}

extern "C" void kernel_launch(void* const* d_in, const int* in_sizes, int n_in,
                              void* d_out, int out_size, void* d_ws, size_t ws_size,
                              hipStream_t stream) {
    const float* x        = (const float*)d_in[0];
    const float* box_lb   = (const float*)d_in[1];
    const float* box_ub   = (const float*)d_in[2];
    const float* group_A  = (const float*)d_in[3];
    const float* group_lb = (const float*)d_in[4];
    const float* group_ub = (const float*)d_in[5];
    const int*   num_iter = (const int*)d_in[6];
    float* out = (float*)d_out;

    const int nrows = in_sizes[0] / NA;          // 262144
    const int total_threads = nrows * 8;         // 8 lanes per row
    const int block = 256;
    const int grid = (total_threads + block - 1) / block;

    proj_kernel<<<grid, block, 0, stream>>>(x, box_lb, box_ub, group_A,
                                            group_lb, group_ub, num_iter,
                                            out, nrows);
}